// Round 3
// baseline (183.386 us; speedup 1.0000x reference)
//
#include <hip/hip_runtime.h>
#include <hip/hip_bf16.h>

#define N_NODES 10000
#define N_EDGES 100000
#define SLOTS 40   // max degree bound; Poisson(10), P(deg>=40) ~ 1e-12

typedef __attribute__((ext_vector_type(8))) short short8;
typedef __attribute__((ext_vector_type(4))) short shortx4;
typedef __attribute__((ext_vector_type(4))) float f32x4;

static __device__ inline short bf16bits(float x) {
    union { __bf16 b; short s; } u;
    u.b = (__bf16)x;
    return u.s;
}
static __device__ inline unsigned short bf16u(float x) {
    union { __bf16 b; unsigned short s; } u;
    u.b = (__bf16)x;
    return u.s;
}
static __device__ inline float bf2f(unsigned short us) {
    union { unsigned int u; float f; } c;
    c.u = ((unsigned int)us) << 16;
    return c.f;
}
static __device__ inline short8 cvt8(const float* f) {
    short8 r;
#pragma unroll
    for (int j = 0; j < 8; ++j) r[j] = bf16bits(f[j]);
    return r;
}

// ---------------------------------------------------------------------------
// Prep kernel (fold-only): 64 blocks x 1024 threads.
//  - threads 0..32767: fold L1s/L1v into Wgen -> Wc (bf16 B-frag order)
//  - threads 32768..65535: fold L2s/L2v into WS0/WS1 -> WB0/WB1
//  - cnt[0..N_NODES) zeroed here (per-node slot counters).
// ---------------------------------------------------------------------------
__global__ __launch_bounds__(1024) void prep_kernel(
    const float* __restrict__ Wgen, const float* __restrict__ L1s,
    const float* __restrict__ L1v, const float* __restrict__ WS0,
    const float* __restrict__ WS1, const float* __restrict__ L2s,
    const float* __restrict__ L2v, unsigned short* __restrict__ Wc,
    unsigned short* __restrict__ WB0, unsigned short* __restrict__ WB1,
    int* __restrict__ cnt) {
    const float S = 1.0f / 128.0f;
    int tid = blockIdx.x * 1024 + threadIdx.x;   // 0..65535
    if (tid < N_NODES) cnt[tid] = 0;             // per-node slot counters
    if (tid < 32768) {
        int j = tid & 7;
        int lane = (tid >> 3) & 63;
        int ks = (tid >> 9) & 7;
        int nt = tid >> 12;
        int col = nt * 16 + (lane & 15);
        int u = (lane >> 4) * 8 + j;
        int r = ks;
        int p, c2;
        const float* M;
        float sc = S;
        if (col < 32)      { p = 0; M = L1s; c2 = col; }
        else if (col < 64) { p = 1; M = L1v; c2 = col - 32; }
        else if (col < 96) { p = 2; M = L1v; c2 = col - 64; }
        else               { p = 3; M = L1s; c2 = col - 96; sc = S * 0.57735026918962576f; }
        const float* wg = Wgen + r * 4096 + p * 1024 + u * 32;
        float acc = 0.f;
#pragma unroll
        for (int w = 0; w < 32; ++w) acc += wg[w] * M[w * 32 + c2];
        Wc[tid] = bf16u(acc * sc);
    } else {
        int idx = tid - 32768;
        int table = idx >> 14;
        int r14 = idx & 16383;
        int j = r14 & 7;
        int lane = (r14 >> 3) & 63;
        int ks = (r14 >> 9) & 15;
        int k = ks * 32 + (lane >> 4) * 8 + j;
        int u = k >> 4, v = k & 15;
        int w = ((r14 >> 13) & 1) * 16 + (lane & 15);
        const float* WS = table ? WS1 : WS0;
        const float* L2 = table ? L2v : L2s;
        const float* src = WS + u * 512 + v * 32;
        float acc = 0.f;
#pragma unroll
        for (int x = 0; x < 32; ++x) acc += src[x] * L2[x * 32 + w];
        unsigned short val = bf16u(acc * S);
        if (table) WB1[r14] = val; else WB0[r14] = val;
    }
}

// ---------------------------------------------------------------------------
// Edge kernel v9: OCCUPANCY PACKAGE.
//  - 512-thread blocks, grid=256: one block per CU, 8 waves/block ->
//    2 waves/SIMD co-resident BY CONSTRUCTION (R2 counters showed ~1
//    wave/SIMD effective: Occupancy 9.4%, 75% stall).
//  - eaR[4] register array replaced by LDS strip sEA (lanes<16 already hold
//    those exact edge_attrs rows as eaC): -16 VGPR, -4 global loads/tile.
//  - static-stride pipelined tile loop otherwise unchanged.
// ---------------------------------------------------------------------------
__global__ __launch_bounds__(512) void edge_kernel(
    const float* __restrict__ node_feats, const float* __restrict__ edge_attrs,
    const float* __restrict__ edge_feats, const int* __restrict__ edge_index,
    const unsigned short* __restrict__ Wc, int* __restrict__ cnt,
    unsigned short* __restrict__ Msg) {
    __shared__ short8 sW8[4096];    // 64 KB, B-fragment order
    __shared__ int sSL[8][16];      // per-wave slot strip
    __shared__ f32x4 sEA[8][16];    // per-wave edge_attrs strip
    {
        const short8* src = (const short8*)Wc;
        for (int i = threadIdx.x; i < 4096; i += 512) sW8[i] = src[i];
    }
    __syncthreads();

    const int lane = threadIdx.x & 63;
    const int m = lane & 15, q = lane >> 4;
    const int wv = threadIdx.x >> 6;
    const int wave = (blockIdx.x * 512 + threadIdx.x) >> 6;
    const int stride = gridDim.x * 8;
    const int NT = N_EDGES / 16;

    int tile = wave;
    if (tile >= NT) return;

    float xsC[8], xvC[24], efC[8];
    f32x4 eaC;
    int slC = 0;

    {
        int e = tile * 16 + m;
        int snd = edge_index[e];
        if (lane < 16) {
            int r = edge_index[N_EDGES + e];
            slC = r * SLOTS + atomicAdd(&cnt[r], 1);
        }
        const float* g = node_feats + snd * 128;
        *(f32x4*)&xsC[0] = *(const f32x4*)(g + q * 8);
        *(f32x4*)&xsC[4] = *(const f32x4*)(g + q * 8 + 4);
#pragma unroll
        for (int i = 0; i < 6; ++i)
            *(f32x4*)&xvC[i * 4] = *(const f32x4*)(g + 32 + q * 24 + i * 4);
        *(f32x4*)&efC[0] = *(const f32x4*)(edge_feats + e * 8);
        *(f32x4*)&efC[4] = *(const f32x4*)(edge_feats + e * 8 + 4);
        eaC = *(const f32x4*)(edge_attrs + e * 4);
    }

    while (tile < NT) {
        const int tn = tile + stride;
        const bool hasN = tn < NT;

        // ---- publish current slots + edge_attrs rows to LDS strips
        if (lane < 16) {
            sSL[wv][lane] = slC;
            sEA[wv][lane] = eaC;
        }

        // ---- prefetch next tile's state
        float xsN[8], xvN[24], efN[8];
        f32x4 eaN;
        int slN = 0;
        if (hasN) {
            int en = tn * 16 + m;
            int sndN = edge_index[en];
            if (lane < 16) {
                int r = edge_index[N_EDGES + en];
                slN = r * SLOTS + atomicAdd(&cnt[r], 1);
            }
            const float* gN = node_feats + sndN * 128;
            *(f32x4*)&xsN[0] = *(const f32x4*)(gN + q * 8);
            *(f32x4*)&xsN[4] = *(const f32x4*)(gN + q * 8 + 4);
#pragma unroll
            for (int i = 0; i < 6; ++i)
                *(f32x4*)&xvN[i * 4] = *(const f32x4*)(gN + 32 + q * 24 + i * 4);
            *(f32x4*)&efN[0] = *(const f32x4*)(edge_feats + en * 8);
            *(f32x4*)&efN[4] = *(const f32x4*)(edge_feats + en * 8 + 4);
            eaN = *(const f32x4*)(edge_attrs + en * 4);
        }

        // ---- compute current tile
        float dt[8];
        {
            float y0 = eaC.y, y1 = eaC.z, y2 = eaC.w;
#pragma unroll
            for (int j = 0; j < 8; ++j)
                dt[j] = xvC[j * 3] * y0 + xvC[j * 3 + 1] * y1 + xvC[j * 3 + 2] * y2;
        }

        f32x4 z = {0.f, 0.f, 0.f, 0.f};
        f32x4 fA[2] = {z, z}, fB[2] = {z, z}, fD[2] = {z, z};
        f32x4 fC[3][2] = {{z, z}, {z, z}, {z, z}};

#pragma unroll
        for (int ks = 0; ks < 8; ++ks) {
            float h = efC[ks];
            float t[8];
#pragma unroll
            for (int j = 0; j < 8; ++j) t[j] = h * xsC[j];
            {
                short8 a = cvt8(t);
                fA[0] = __builtin_amdgcn_mfma_f32_16x16x32_bf16(a, sW8[(0 * 8 + ks) * 64 + lane], fA[0], 0, 0, 0);
                fA[1] = __builtin_amdgcn_mfma_f32_16x16x32_bf16(a, sW8[(1 * 8 + ks) * 64 + lane], fA[1], 0, 0, 0);
                fB[0] = __builtin_amdgcn_mfma_f32_16x16x32_bf16(a, sW8[(2 * 8 + ks) * 64 + lane], fB[0], 0, 0, 0);
                fB[1] = __builtin_amdgcn_mfma_f32_16x16x32_bf16(a, sW8[(3 * 8 + ks) * 64 + lane], fB[1], 0, 0, 0);
            }
            {
                short8 bc0 = sW8[(4 * 8 + ks) * 64 + lane];
                short8 bc1 = sW8[(5 * 8 + ks) * 64 + lane];
#pragma unroll
                for (int c = 0; c < 3; ++c) {
#pragma unroll
                    for (int j = 0; j < 8; ++j) t[j] = h * xvC[j * 3 + c];
                    short8 a = cvt8(t);
                    fC[c][0] = __builtin_amdgcn_mfma_f32_16x16x32_bf16(a, bc0, fC[c][0], 0, 0, 0);
                    fC[c][1] = __builtin_amdgcn_mfma_f32_16x16x32_bf16(a, bc1, fC[c][1], 0, 0, 0);
                }
            }
            {
#pragma unroll
                for (int j = 0; j < 8; ++j) t[j] = h * dt[j];
                short8 a = cvt8(t);
                fD[0] = __builtin_amdgcn_mfma_f32_16x16x32_bf16(a, sW8[(6 * 8 + ks) * 64 + lane], fD[0], 0, 0, 0);
                fD[1] = __builtin_amdgcn_mfma_f32_16x16x32_bf16(a, sW8[(7 * 8 + ks) * 64 + lane], fD[1], 0, 0, 0);
            }
        }

        // ---- epilogue: per-lane rows q*4+t4; slots+attrs via ds_read_b128
        int4 sl4 = *(const int4*)&sSL[wv][q * 4];
        const int slR[4] = {sl4.x, sl4.y, sl4.z, sl4.w};
#pragma unroll
        for (int t4 = 0; t4 < 4; ++t4) {
            f32x4 ea4 = sEA[wv][q * 4 + t4];
            float ysr = ea4.x, y0r = ea4.y, y1r = ea4.z, y2r = ea4.w;
            int dr = slR[t4];
#pragma unroll
            for (int nt = 0; nt < 2; ++nt) {
                int col = nt * 16 + m;
                float pb = fB[nt][t4];
                shortx4 pk;
                pk[0] = bf16bits(ysr * fA[nt][t4] + fD[nt][t4]);
                pk[1] = bf16bits(y0r * pb + ysr * fC[0][nt][t4]);
                pk[2] = bf16bits(y1r * pb + ysr * fC[1][nt][t4]);
                pk[3] = bf16bits(y2r * pb + ysr * fC[2][nt][t4]);
                *(shortx4*)(Msg + (size_t)dr * 128 + col * 4) = pk;
            }
        }

        // ---- rotate pipeline
        tile = tn;
        if (hasN) {
#pragma unroll
            for (int j = 0; j < 8; ++j) { xsC[j] = xsN[j]; efC[j] = efN[j]; }
#pragma unroll
            for (int j = 0; j < 24; ++j) xvC[j] = xvN[j];
            eaC = eaN;
            slC = slN;
        }
    }
}

// ---------------------------------------------------------------------------
// Fused gather + node kernel. Degree comes from cnt[n]; rows at n*SLOTS.
// ---------------------------------------------------------------------------
__global__ __launch_bounds__(256) void node_kernel(
    const float* __restrict__ node_attrs, const unsigned short* __restrict__ Msg,
    const int* __restrict__ cnt, const unsigned short* __restrict__ WB0,
    const unsigned short* __restrict__ WB1, float* __restrict__ out) {
    __shared__ float sM[16][129];
    __shared__ float sAt[16][17];
    int n0 = blockIdx.x * 16;

    int nl = threadIdx.x >> 4;
    int cg = threadIdx.x & 15;
    int n = n0 + nl;
    int s0 = n * SLOTS;
    int s1 = s0 + cnt[n];
    float acc[8];
#pragma unroll
    for (int j = 0; j < 8; ++j) acc[j] = 0.f;
    int s = s0;
    for (; s + 3 < s1; s += 4) {
        f32x4 r0 = *(const f32x4*)(Msg + (size_t)(s + 0) * 128 + cg * 8);
        f32x4 r1 = *(const f32x4*)(Msg + (size_t)(s + 1) * 128 + cg * 8);
        f32x4 r2 = *(const f32x4*)(Msg + (size_t)(s + 2) * 128 + cg * 8);
        f32x4 r3 = *(const f32x4*)(Msg + (size_t)(s + 3) * 128 + cg * 8);
        const unsigned short* u0 = (const unsigned short*)&r0;
        const unsigned short* u1 = (const unsigned short*)&r1;
        const unsigned short* u2 = (const unsigned short*)&r2;
        const unsigned short* u3 = (const unsigned short*)&r3;
#pragma unroll
        for (int j = 0; j < 8; ++j)
            acc[j] += (bf2f(u0[j]) + bf2f(u1[j])) + (bf2f(u2[j]) + bf2f(u3[j]));
    }
    for (; s < s1; ++s) {
        f32x4 raw = *(const f32x4*)(Msg + (size_t)s * 128 + cg * 8);
        const unsigned short* us = (const unsigned short*)&raw;
#pragma unroll
        for (int j = 0; j < 8; ++j) acc[j] += bf2f(us[j]);
    }
#pragma unroll
    for (int j = 0; j < 8; ++j)
        sM[nl][(j & 3) * 32 + cg * 2 + (j >> 2)] = acc[j];
    sAt[nl][cg] = node_attrs[n * 16 + cg];
    __syncthreads();

    int p = threadIdx.x >> 6;
    int lane = threadIdx.x & 63;
    int m = lane & 15, q = lane >> 4;
    const unsigned short* WB = (p == 0) ? WB0 : WB1;
    int chb = p * 32;
    f32x4 z = {0.f, 0.f, 0.f, 0.f};
    f32x4 D0 = z, D1 = z;
#pragma unroll
    for (int ks = 0; ks < 16; ++ks) {
        int kb = ks * 32 + q * 8;
        float t[8];
#pragma unroll
        for (int j = 0; j < 8; ++j) {
            int k = kb + j;
            t[j] = sM[m][chb + (k >> 4)] * sAt[m][k & 15];
        }
        short8 a = cvt8(t);
        short8 b0 = *(const short8*)(WB + (ks * 64 + lane) * 8);
        short8 b1 = *(const short8*)(WB + ((16 + ks) * 64 + lane) * 8);
        D0 = __builtin_amdgcn_mfma_f32_16x16x32_bf16(a, b0, D0, 0, 0, 0);
        D1 = __builtin_amdgcn_mfma_f32_16x16x32_bf16(a, b1, D1, 0, 0, 0);
    }

#pragma unroll
    for (int t4 = 0; t4 < 4; ++t4) {
        int nl2 = q * 4 + t4;
        int nn = n0 + nl2;
        if (p == 0) {
            out[nn * 128 + m]      = sM[nl2][m] + D0[t4];
            out[nn * 128 + 16 + m] = sM[nl2][16 + m] + D1[t4];
        } else {
            int i = p - 1;
            out[nn * 128 + 32 + m * 3 + i]        = sM[nl2][chb + m] + D0[t4];
            out[nn * 128 + 32 + (16 + m) * 3 + i] = sM[nl2][chb + 16 + m] + D1[t4];
        }
    }
}

extern "C" void kernel_launch(void* const* d_in, const int* in_sizes, int n_in,
                              void* d_out, int out_size, void* d_ws, size_t ws_size,
                              hipStream_t stream) {
    (void)in_sizes; (void)n_in; (void)out_size; (void)ws_size;
    const float* node_attrs = (const float*)d_in[0];
    const float* node_feats = (const float*)d_in[1];
    const float* edge_attrs = (const float*)d_in[2];
    const float* edge_feats = (const float*)d_in[3];
    const int*   edge_index = (const int*)d_in[4];
    const float* Wgen = (const float*)d_in[5];
    const float* L1s  = (const float*)d_in[6];
    const float* L1v  = (const float*)d_in[7];
    const float* WS0  = (const float*)d_in[8];
    const float* WS1  = (const float*)d_in[9];
    const float* L2s  = (const float*)d_in[10];
    const float* L2v  = (const float*)d_in[11];
    float* out = (float*)d_out;
    char* ws = (char*)d_ws;

    // Msg: N_NODES*SLOTS rows x 128 bf16 = 102,400,000 B (ws is 256 MiB)
    unsigned short* Msg = (unsigned short*)ws;
    unsigned short* Wc  = (unsigned short*)(ws + 102400000);   // 65,536
    unsigned short* WB0 = (unsigned short*)(ws + 102465536);   // 32,768
    unsigned short* WB1 = (unsigned short*)(ws + 102498304);   // 32,768
    int* cnt = (int*)(ws + 102531072);                         // 10000 ints

    prep_kernel<<<64, 1024, 0, stream>>>(Wgen, L1s, L1v, WS0, WS1, L2s, L2v,
                                         Wc, WB0, WB1, cnt);
    edge_kernel<<<256, 512, 0, stream>>>(node_feats, edge_attrs, edge_feats,
                                         edge_index, Wc, cnt, Msg);
    node_kernel<<<625, 256, 0, stream>>>(node_attrs, Msg, cnt, WB0, WB1, out);
}

// Round 4
// 131.078 us; speedup vs baseline: 1.3991x; 1.3991x over previous
//
#include <hip/hip_runtime.h>
#include <hip/hip_bf16.h>

#define N_NODES 10000
#define N_EDGES 100000
#define SLOTS 40   // max degree bound; Poisson(10), P(deg>=40) ~ 1e-12

typedef __attribute__((ext_vector_type(8))) short short8;
typedef __attribute__((ext_vector_type(4))) short shortx4;
typedef __attribute__((ext_vector_type(4))) float f32x4;

static __device__ inline short bf16bits(float x) {
    union { __bf16 b; short s; } u;
    u.b = (__bf16)x;
    return u.s;
}
static __device__ inline unsigned short bf16u(float x) {
    union { __bf16 b; unsigned short s; } u;
    u.b = (__bf16)x;
    return u.s;
}
static __device__ inline float bf2f(unsigned short us) {
    union { unsigned int u; float f; } c;
    c.u = ((unsigned int)us) << 16;
    return c.f;
}
static __device__ inline short8 cvt8(const float* f) {
    short8 r;
#pragma unroll
    for (int j = 0; j < 8; ++j) r[j] = bf16bits(f[j]);
    return r;
}

// ---------------------------------------------------------------------------
// Prep kernel (fold-only): 64 blocks x 1024 threads.
// ---------------------------------------------------------------------------
__global__ __launch_bounds__(1024) void prep_kernel(
    const float* __restrict__ Wgen, const float* __restrict__ L1s,
    const float* __restrict__ L1v, const float* __restrict__ WS0,
    const float* __restrict__ WS1, const float* __restrict__ L2s,
    const float* __restrict__ L2v, unsigned short* __restrict__ Wc,
    unsigned short* __restrict__ WB0, unsigned short* __restrict__ WB1,
    int* __restrict__ cnt) {
    const float S = 1.0f / 128.0f;
    int tid = blockIdx.x * 1024 + threadIdx.x;   // 0..65535
    if (tid < N_NODES) cnt[tid] = 0;             // per-node slot counters
    if (tid < 32768) {
        int j = tid & 7;
        int lane = (tid >> 3) & 63;
        int ks = (tid >> 9) & 7;
        int nt = tid >> 12;
        int col = nt * 16 + (lane & 15);
        int u = (lane >> 4) * 8 + j;
        int r = ks;
        int p, c2;
        const float* M;
        float sc = S;
        if (col < 32)      { p = 0; M = L1s; c2 = col; }
        else if (col < 64) { p = 1; M = L1v; c2 = col - 32; }
        else if (col < 96) { p = 2; M = L1v; c2 = col - 64; }
        else               { p = 3; M = L1s; c2 = col - 96; sc = S * 0.57735026918962576f; }
        const float* wg = Wgen + r * 4096 + p * 1024 + u * 32;
        float acc = 0.f;
#pragma unroll
        for (int w = 0; w < 32; ++w) acc += wg[w] * M[w * 32 + c2];
        Wc[tid] = bf16u(acc * sc);
    } else {
        int idx = tid - 32768;
        int table = idx >> 14;
        int r14 = idx & 16383;
        int j = r14 & 7;
        int lane = (r14 >> 3) & 63;
        int ks = (r14 >> 9) & 15;
        int k = ks * 32 + (lane >> 4) * 8 + j;
        int u = k >> 4, v = k & 15;
        int w = ((r14 >> 13) & 1) * 16 + (lane & 15);
        const float* WS = table ? WS1 : WS0;
        const float* L2 = table ? L2v : L2s;
        const float* src = WS + u * 512 + v * 32;
        float acc = 0.f;
#pragma unroll
        for (int x = 0; x < 32; ++x) acc += src[x] * L2[x * 32 + w];
        unsigned short val = bf16u(acc * S);
        if (table) WB1[r14] = val; else WB0[r14] = val;
    }
}

// ---------------------------------------------------------------------------
// Edge kernel v10: R2 shape (256 thr, grid 512, NO reg cap -> no spills;
// R3's launch_bounds(512) forced VGPR=128 and spilled 130 MB of scratch).
// New: 2-DEEP INDEX PREFETCH — indices for tile+s held in registers
// (snd1/rcv1), so the gather+atomic for tile+s issue at loop top with zero
// load-dependency; the idx load for tile+2s issues in parallel. Removes the
// serial idx->gather hop from the per-tile critical path.
// Kept from R3: sEA LDS strip (epilogue edge_attrs rows from eaC, -16 VGPR).
// ---------------------------------------------------------------------------
__global__ __launch_bounds__(256) void edge_kernel(
    const float* __restrict__ node_feats, const float* __restrict__ edge_attrs,
    const float* __restrict__ edge_feats, const int* __restrict__ edge_index,
    const unsigned short* __restrict__ Wc, int* __restrict__ cnt,
    unsigned short* __restrict__ Msg) {
    __shared__ short8 sW8[4096];    // 64 KB, B-fragment order
    __shared__ int sSL[4][16];      // per-wave slot strip
    __shared__ f32x4 sEA[4][16];    // per-wave edge_attrs strip
    {
        const short8* src = (const short8*)Wc;
        for (int i = threadIdx.x; i < 4096; i += 256) sW8[i] = src[i];
    }
    __syncthreads();

    const int lane = threadIdx.x & 63;
    const int m = lane & 15, q = lane >> 4;
    const int wv = threadIdx.x >> 6;
    const int wave = (blockIdx.x * 256 + threadIdx.x) >> 6;
    const int stride = gridDim.x * 4;
    const int NT = N_EDGES / 16;

    int tile = wave;
    if (tile >= NT) return;

    float xsC[8], xvC[24], efC[8];
    f32x4 eaC;
    int slC = 0;

    // ---- prologue: state for tile (serial, once), indices for tile+stride
    {
        int e = tile * 16 + m;
        int snd = edge_index[e];
        if (lane < 16) {
            int r = edge_index[N_EDGES + e];
            slC = r * SLOTS + atomicAdd(&cnt[r], 1);
        }
        const float* g = node_feats + snd * 128;
        *(f32x4*)&xsC[0] = *(const f32x4*)(g + q * 8);
        *(f32x4*)&xsC[4] = *(const f32x4*)(g + q * 8 + 4);
#pragma unroll
        for (int i = 0; i < 6; ++i)
            *(f32x4*)&xvC[i * 4] = *(const f32x4*)(g + 32 + q * 24 + i * 4);
        *(f32x4*)&efC[0] = *(const f32x4*)(edge_feats + e * 8);
        *(f32x4*)&efC[4] = *(const f32x4*)(edge_feats + e * 8 + 4);
        eaC = *(const f32x4*)(edge_attrs + e * 4);
    }
    int snd1 = 0, rcv1 = 0;
    {
        int t1 = tile + stride;
        if (t1 < NT) {
            int e1 = t1 * 16 + m;
            snd1 = edge_index[e1];
            if (lane < 16) rcv1 = edge_index[N_EDGES + e1];
        }
    }

    while (tile < NT) {
        const int tn = tile + stride;
        const bool hasN = tn < NT;
        const int t2 = tile + 2 * stride;
        const bool has2 = t2 < NT;

        // ---- publish current slots + edge_attrs rows to LDS strips
        if (lane < 16) {
            sSL[wv][lane] = slC;
            sEA[wv][lane] = eaC;
        }

        // ---- prefetch tile+s state using in-register indices (no dep wait)
        float xsN[8], xvN[24], efN[8];
        f32x4 eaN;
        int slN = 0;
        if (hasN) {
            int en = tn * 16 + m;
            if (lane < 16) slN = rcv1 * SLOTS + atomicAdd(&cnt[rcv1], 1);
            const float* gN = node_feats + snd1 * 128;
            *(f32x4*)&xsN[0] = *(const f32x4*)(gN + q * 8);
            *(f32x4*)&xsN[4] = *(const f32x4*)(gN + q * 8 + 4);
#pragma unroll
            for (int i = 0; i < 6; ++i)
                *(f32x4*)&xvN[i * 4] = *(const f32x4*)(gN + 32 + q * 24 + i * 4);
            *(f32x4*)&efN[0] = *(const f32x4*)(edge_feats + en * 8);
            *(f32x4*)&efN[4] = *(const f32x4*)(edge_feats + en * 8 + 4);
            eaN = *(const f32x4*)(edge_attrs + en * 4);
        }

        // ---- prefetch tile+2s indices (arrives during this tile's compute)
        int snd2 = 0, rcv2 = 0;
        if (has2) {
            int e2 = t2 * 16 + m;
            snd2 = edge_index[e2];
            if (lane < 16) rcv2 = edge_index[N_EDGES + e2];
        }

        // ---- compute current tile
        float dt[8];
        {
            float y0 = eaC.y, y1 = eaC.z, y2 = eaC.w;
#pragma unroll
            for (int j = 0; j < 8; ++j)
                dt[j] = xvC[j * 3] * y0 + xvC[j * 3 + 1] * y1 + xvC[j * 3 + 2] * y2;
        }

        f32x4 z = {0.f, 0.f, 0.f, 0.f};
        f32x4 fA[2] = {z, z}, fB[2] = {z, z}, fD[2] = {z, z};
        f32x4 fC[3][2] = {{z, z}, {z, z}, {z, z}};

#pragma unroll
        for (int ks = 0; ks < 8; ++ks) {
            float h = efC[ks];
            float t[8];
#pragma unroll
            for (int j = 0; j < 8; ++j) t[j] = h * xsC[j];
            {
                short8 a = cvt8(t);
                fA[0] = __builtin_amdgcn_mfma_f32_16x16x32_bf16(a, sW8[(0 * 8 + ks) * 64 + lane], fA[0], 0, 0, 0);
                fA[1] = __builtin_amdgcn_mfma_f32_16x16x32_bf16(a, sW8[(1 * 8 + ks) * 64 + lane], fA[1], 0, 0, 0);
                fB[0] = __builtin_amdgcn_mfma_f32_16x16x32_bf16(a, sW8[(2 * 8 + ks) * 64 + lane], fB[0], 0, 0, 0);
                fB[1] = __builtin_amdgcn_mfma_f32_16x16x32_bf16(a, sW8[(3 * 8 + ks) * 64 + lane], fB[1], 0, 0, 0);
            }
            {
                short8 bc0 = sW8[(4 * 8 + ks) * 64 + lane];
                short8 bc1 = sW8[(5 * 8 + ks) * 64 + lane];
#pragma unroll
                for (int c = 0; c < 3; ++c) {
#pragma unroll
                    for (int j = 0; j < 8; ++j) t[j] = h * xvC[j * 3 + c];
                    short8 a = cvt8(t);
                    fC[c][0] = __builtin_amdgcn_mfma_f32_16x16x32_bf16(a, bc0, fC[c][0], 0, 0, 0);
                    fC[c][1] = __builtin_amdgcn_mfma_f32_16x16x32_bf16(a, bc1, fC[c][1], 0, 0, 0);
                }
            }
            {
#pragma unroll
                for (int j = 0; j < 8; ++j) t[j] = h * dt[j];
                short8 a = cvt8(t);
                fD[0] = __builtin_amdgcn_mfma_f32_16x16x32_bf16(a, sW8[(6 * 8 + ks) * 64 + lane], fD[0], 0, 0, 0);
                fD[1] = __builtin_amdgcn_mfma_f32_16x16x32_bf16(a, sW8[(7 * 8 + ks) * 64 + lane], fD[1], 0, 0, 0);
            }
        }

        // ---- epilogue: per-lane rows q*4+t4; slots+attrs via ds_read_b128
        int4 sl4 = *(const int4*)&sSL[wv][q * 4];
        const int slR[4] = {sl4.x, sl4.y, sl4.z, sl4.w};
#pragma unroll
        for (int t4 = 0; t4 < 4; ++t4) {
            f32x4 ea4 = sEA[wv][q * 4 + t4];
            float ysr = ea4.x, y0r = ea4.y, y1r = ea4.z, y2r = ea4.w;
            int dr = slR[t4];
#pragma unroll
            for (int nt = 0; nt < 2; ++nt) {
                int col = nt * 16 + m;
                float pb = fB[nt][t4];
                shortx4 pk;
                pk[0] = bf16bits(ysr * fA[nt][t4] + fD[nt][t4]);
                pk[1] = bf16bits(y0r * pb + ysr * fC[0][nt][t4]);
                pk[2] = bf16bits(y1r * pb + ysr * fC[1][nt][t4]);
                pk[3] = bf16bits(y2r * pb + ysr * fC[2][nt][t4]);
                *(shortx4*)(Msg + (size_t)dr * 128 + col * 4) = pk;
            }
        }

        // ---- rotate pipeline
        tile = tn;
        if (hasN) {
#pragma unroll
            for (int j = 0; j < 8; ++j) { xsC[j] = xsN[j]; efC[j] = efN[j]; }
#pragma unroll
            for (int j = 0; j < 24; ++j) xvC[j] = xvN[j];
            eaC = eaN;
            slC = slN;
            snd1 = snd2;
            rcv1 = rcv2;
        }
    }
}

// ---------------------------------------------------------------------------
// Fused gather + node kernel. Degree comes from cnt[n]; rows at n*SLOTS.
// ---------------------------------------------------------------------------
__global__ __launch_bounds__(256) void node_kernel(
    const float* __restrict__ node_attrs, const unsigned short* __restrict__ Msg,
    const int* __restrict__ cnt, const unsigned short* __restrict__ WB0,
    const unsigned short* __restrict__ WB1, float* __restrict__ out) {
    __shared__ float sM[16][129];
    __shared__ float sAt[16][17];
    int n0 = blockIdx.x * 16;

    int nl = threadIdx.x >> 4;
    int cg = threadIdx.x & 15;
    int n = n0 + nl;
    int s0 = n * SLOTS;
    int s1 = s0 + cnt[n];
    float acc[8];
#pragma unroll
    for (int j = 0; j < 8; ++j) acc[j] = 0.f;
    int s = s0;
    for (; s + 3 < s1; s += 4) {
        f32x4 r0 = *(const f32x4*)(Msg + (size_t)(s + 0) * 128 + cg * 8);
        f32x4 r1 = *(const f32x4*)(Msg + (size_t)(s + 1) * 128 + cg * 8);
        f32x4 r2 = *(const f32x4*)(Msg + (size_t)(s + 2) * 128 + cg * 8);
        f32x4 r3 = *(const f32x4*)(Msg + (size_t)(s + 3) * 128 + cg * 8);
        const unsigned short* u0 = (const unsigned short*)&r0;
        const unsigned short* u1 = (const unsigned short*)&r1;
        const unsigned short* u2 = (const unsigned short*)&r2;
        const unsigned short* u3 = (const unsigned short*)&r3;
#pragma unroll
        for (int j = 0; j < 8; ++j)
            acc[j] += (bf2f(u0[j]) + bf2f(u1[j])) + (bf2f(u2[j]) + bf2f(u3[j]));
    }
    for (; s < s1; ++s) {
        f32x4 raw = *(const f32x4*)(Msg + (size_t)s * 128 + cg * 8);
        const unsigned short* us = (const unsigned short*)&raw;
#pragma unroll
        for (int j = 0; j < 8; ++j) acc[j] += bf2f(us[j]);
    }
#pragma unroll
    for (int j = 0; j < 8; ++j)
        sM[nl][(j & 3) * 32 + cg * 2 + (j >> 2)] = acc[j];
    sAt[nl][cg] = node_attrs[n * 16 + cg];
    __syncthreads();

    int p = threadIdx.x >> 6;
    int lane = threadIdx.x & 63;
    int m = lane & 15, q = lane >> 4;
    const unsigned short* WB = (p == 0) ? WB0 : WB1;
    int chb = p * 32;
    f32x4 z = {0.f, 0.f, 0.f, 0.f};
    f32x4 D0 = z, D1 = z;
#pragma unroll
    for (int ks = 0; ks < 16; ++ks) {
        int kb = ks * 32 + q * 8;
        float t[8];
#pragma unroll
        for (int j = 0; j < 8; ++j) {
            int k = kb + j;
            t[j] = sM[m][chb + (k >> 4)] * sAt[m][k & 15];
        }
        short8 a = cvt8(t);
        short8 b0 = *(const short8*)(WB + (ks * 64 + lane) * 8);
        short8 b1 = *(const short8*)(WB + ((16 + ks) * 64 + lane) * 8);
        D0 = __builtin_amdgcn_mfma_f32_16x16x32_bf16(a, b0, D0, 0, 0, 0);
        D1 = __builtin_amdgcn_mfma_f32_16x16x32_bf16(a, b1, D1, 0, 0, 0);
    }

#pragma unroll
    for (int t4 = 0; t4 < 4; ++t4) {
        int nl2 = q * 4 + t4;
        int nn = n0 + nl2;
        if (p == 0) {
            out[nn * 128 + m]      = sM[nl2][m] + D0[t4];
            out[nn * 128 + 16 + m] = sM[nl2][16 + m] + D1[t4];
        } else {
            int i = p - 1;
            out[nn * 128 + 32 + m * 3 + i]        = sM[nl2][chb + m] + D0[t4];
            out[nn * 128 + 32 + (16 + m) * 3 + i] = sM[nl2][chb + 16 + m] + D1[t4];
        }
    }
}

extern "C" void kernel_launch(void* const* d_in, const int* in_sizes, int n_in,
                              void* d_out, int out_size, void* d_ws, size_t ws_size,
                              hipStream_t stream) {
    (void)in_sizes; (void)n_in; (void)out_size; (void)ws_size;
    const float* node_attrs = (const float*)d_in[0];
    const float* node_feats = (const float*)d_in[1];
    const float* edge_attrs = (const float*)d_in[2];
    const float* edge_feats = (const float*)d_in[3];
    const int*   edge_index = (const int*)d_in[4];
    const float* Wgen = (const float*)d_in[5];
    const float* L1s  = (const float*)d_in[6];
    const float* L1v  = (const float*)d_in[7];
    const float* WS0  = (const float*)d_in[8];
    const float* WS1  = (const float*)d_in[9];
    const float* L2s  = (const float*)d_in[10];
    const float* L2v  = (const float*)d_in[11];
    float* out = (float*)d_out;
    char* ws = (char*)d_ws;

    // Msg: N_NODES*SLOTS rows x 128 bf16 = 102,400,000 B (ws is 256 MiB)
    unsigned short* Msg = (unsigned short*)ws;
    unsigned short* Wc  = (unsigned short*)(ws + 102400000);   // 65,536
    unsigned short* WB0 = (unsigned short*)(ws + 102465536);   // 32,768
    unsigned short* WB1 = (unsigned short*)(ws + 102498304);   // 32,768
    int* cnt = (int*)(ws + 102531072);                         // 10000 ints

    prep_kernel<<<64, 1024, 0, stream>>>(Wgen, L1s, L1v, WS0, WS1, L2s, L2v,
                                         Wc, WB0, WB1, cnt);
    edge_kernel<<<512, 256, 0, stream>>>(node_feats, edge_attrs, edge_feats,
                                         edge_index, Wc, cnt, Msg);
    node_kernel<<<625, 256, 0, stream>>>(node_attrs, Msg, cnt, WB0, WB1, out);
}

// Round 6
// 126.903 us; speedup vs baseline: 1.4451x; 1.0329x over previous
//
#include <hip/hip_runtime.h>

#define N_NODES 10000
#define N_EDGES 100000
#define SLOTS 40   // max degree bound; Poisson(10), P(deg>=40) ~ 1e-12

typedef __attribute__((ext_vector_type(8))) _Float16 f16x8;
typedef __attribute__((ext_vector_type(2))) _Float16 f16x2;
typedef __attribute__((ext_vector_type(4))) float f32x4;

// __builtin_amdgcn_cvt_pkrtz returns __fp16x2; rewrap bits as _Float16x2.
static __device__ inline f16x2 pkrtz(float a, float b) {
    auto t = __builtin_amdgcn_cvt_pkrtz(a, b);
    union { decltype(t) x; f16x2 y; } u;
    u.x = t;
    return u.y;
}
static __device__ inline unsigned short f16u(float x) {
    union { _Float16 h; unsigned short s; } u;
    u.h = (_Float16)x;
    return u.s;
}
static __device__ inline float f16f(unsigned short us) {
    union { unsigned short s; _Float16 h; } u;
    u.s = us;
    return (float)u.h;
}
// 4x v_cvt_pkrtz_f16_f32: 8 f32 -> f16x8
static __device__ inline f16x8 cvt8h(const float* f) {
    f16x8 r; f16x2* rp = (f16x2*)&r;
#pragma unroll
    for (int i = 0; i < 4; ++i) rp[i] = pkrtz(f[2 * i], f[2 * i + 1]);
    return r;
}
// 4x v_pk_mul_f16: broadcast-scale an f16x8
static __device__ inline f16x8 scale8(f16x2 h2, f16x8 x) {
    f16x8 r; f16x2* rp = (f16x2*)&r; f16x2* xp = (f16x2*)&x;
#pragma unroll
    for (int i = 0; i < 4; ++i) rp[i] = h2 * xp[i];
    return r;
}
static __device__ inline int pack2(float a, float b) {
    union { f16x2 h; int i; } u;
    u.h = pkrtz(a, b);
    return u.i;
}

// ---------------------------------------------------------------------------
// Prep kernel (fold-only): 64 blocks x 1024 threads. Tables emitted as F16.
// ---------------------------------------------------------------------------
__global__ __launch_bounds__(1024) void prep_kernel(
    const float* __restrict__ Wgen, const float* __restrict__ L1s,
    const float* __restrict__ L1v, const float* __restrict__ WS0,
    const float* __restrict__ WS1, const float* __restrict__ L2s,
    const float* __restrict__ L2v, unsigned short* __restrict__ Wc,
    unsigned short* __restrict__ WB0, unsigned short* __restrict__ WB1,
    int* __restrict__ cnt) {
    const float S = 1.0f / 128.0f;
    int tid = blockIdx.x * 1024 + threadIdx.x;   // 0..65535
    if (tid < N_NODES) cnt[tid] = 0;             // per-node slot counters
    if (tid < 32768) {
        int j = tid & 7;
        int lane = (tid >> 3) & 63;
        int ks = (tid >> 9) & 7;
        int nt = tid >> 12;
        int col = nt * 16 + (lane & 15);
        int u = (lane >> 4) * 8 + j;
        int r = ks;
        int p, c2;
        const float* M;
        float sc = S;
        if (col < 32)      { p = 0; M = L1s; c2 = col; }
        else if (col < 64) { p = 1; M = L1v; c2 = col - 32; }
        else if (col < 96) { p = 2; M = L1v; c2 = col - 64; }
        else               { p = 3; M = L1s; c2 = col - 96; sc = S * 0.57735026918962576f; }
        const float* wg = Wgen + r * 4096 + p * 1024 + u * 32;
        float acc = 0.f;
#pragma unroll
        for (int w = 0; w < 32; ++w) acc += wg[w] * M[w * 32 + c2];
        Wc[tid] = f16u(acc * sc);
    } else {
        int idx = tid - 32768;
        int table = idx >> 14;
        int r14 = idx & 16383;
        int j = r14 & 7;
        int lane = (r14 >> 3) & 63;
        int ks = (r14 >> 9) & 15;
        int k = ks * 32 + (lane >> 4) * 8 + j;
        int u = k >> 4, v = k & 15;
        int w = ((r14 >> 13) & 1) * 16 + (lane & 15);
        const float* WS = table ? WS1 : WS0;
        const float* L2 = table ? L2v : L2s;
        const float* src = WS + u * 512 + v * 32;
        float acc = 0.f;
#pragma unroll
        for (int x = 0; x < 32; ++x) acc += src[x] * L2[x * 32 + w];
        unsigned short val = f16u(acc * S);
        if (table) WB1[r14] = val; else WB0[r14] = val;
    }
}

// ---------------------------------------------------------------------------
// Edge kernel v11: F16 PACKED DATAPATH.
//  - pipeline state held as f16x8 (xs8, xv8[3], dt8); converted ONCE per tile
//    at rotate via v_cvt_pkrtz (2 vals/inst).
//  - A-frag build: 4x v_pk_mul_f16 (was 8 mul + 8 cvt).
//  - MFMA f32_16x16x32_f16 (same rate/layout as bf16).
//  - kept: 2-deep index prefetch, sEA/sSL strips, static stride, 256 thr.
// ---------------------------------------------------------------------------
__global__ __launch_bounds__(256) void edge_kernel(
    const float* __restrict__ node_feats, const float* __restrict__ edge_attrs,
    const float* __restrict__ edge_feats, const int* __restrict__ edge_index,
    const unsigned short* __restrict__ Wc, int* __restrict__ cnt,
    unsigned short* __restrict__ Msg) {
    __shared__ f16x8 sW8[4096];     // 64 KB, B-fragment order (f16 bits)
    __shared__ int sSL[4][16];      // per-wave slot strip
    __shared__ f32x4 sEA[4][16];    // per-wave edge_attrs strip
    {
        const f16x8* src = (const f16x8*)Wc;
        for (int i = threadIdx.x; i < 4096; i += 256) sW8[i] = src[i];
    }
    __syncthreads();

    const int lane = threadIdx.x & 63;
    const int m = lane & 15, q = lane >> 4;
    const int wv = threadIdx.x >> 6;
    const int wave = (blockIdx.x * 256 + threadIdx.x) >> 6;
    const int stride = gridDim.x * 4;
    const int NT = N_EDGES / 16;

    int tile = wave;
    if (tile >= NT) return;

    // converted pipeline state for current tile
    f16x8 xs8, xv8[3], dt8;
    float efC[8];
    f32x4 eaC;
    int slC = 0;

    // ---- prologue: gather + convert for first tile; idx prefetch for +stride
    {
        int e = tile * 16 + m;
        int snd = edge_index[e];
        if (lane < 16) {
            int r = edge_index[N_EDGES + e];
            slC = r * SLOTS + atomicAdd(&cnt[r], 1);
        }
        const float* g = node_feats + snd * 128;
        float xs[8], xv[24];
        *(f32x4*)&xs[0] = *(const f32x4*)(g + q * 8);
        *(f32x4*)&xs[4] = *(const f32x4*)(g + q * 8 + 4);
#pragma unroll
        for (int i = 0; i < 6; ++i)
            *(f32x4*)&xv[i * 4] = *(const f32x4*)(g + 32 + q * 24 + i * 4);
        *(f32x4*)&efC[0] = *(const f32x4*)(edge_feats + e * 8);
        *(f32x4*)&efC[4] = *(const f32x4*)(edge_feats + e * 8 + 4);
        eaC = *(const f32x4*)(edge_attrs + e * 4);
        float dt[8];
        float y0 = eaC.y, y1 = eaC.z, y2 = eaC.w;
#pragma unroll
        for (int j = 0; j < 8; ++j)
            dt[j] = xv[j * 3] * y0 + xv[j * 3 + 1] * y1 + xv[j * 3 + 2] * y2;
        xs8 = cvt8h(xs);
#pragma unroll
        for (int c = 0; c < 3; ++c) {
            f16x8 r; f16x2* rp = (f16x2*)&r;
#pragma unroll
            for (int i = 0; i < 4; ++i)
                rp[i] = pkrtz(xv[(2 * i) * 3 + c], xv[(2 * i + 1) * 3 + c]);
            xv8[c] = r;
        }
        dt8 = cvt8h(dt);
    }
    int snd1 = 0, rcv1 = 0;
    {
        int t1 = tile + stride;
        if (t1 < NT) {
            int e1 = t1 * 16 + m;
            snd1 = edge_index[e1];
            if (lane < 16) rcv1 = edge_index[N_EDGES + e1];
        }
    }

    while (tile < NT) {
        const int tn = tile + stride;
        const bool hasN = tn < NT;
        const int t2 = tile + 2 * stride;
        const bool has2 = t2 < NT;

        // ---- publish current slots + edge_attrs rows to LDS strips
        if (lane < 16) {
            sSL[wv][lane] = slC;
            sEA[wv][lane] = eaC;
        }

        // ---- prefetch tile+s raw state (in-register indices, no dep wait)
        float xsN[8], xvN[24], efN[8];
        f32x4 eaN;
        int slN = 0;
        if (hasN) {
            int en = tn * 16 + m;
            if (lane < 16) slN = rcv1 * SLOTS + atomicAdd(&cnt[rcv1], 1);
            const float* gN = node_feats + snd1 * 128;
            *(f32x4*)&xsN[0] = *(const f32x4*)(gN + q * 8);
            *(f32x4*)&xsN[4] = *(const f32x4*)(gN + q * 8 + 4);
#pragma unroll
            for (int i = 0; i < 6; ++i)
                *(f32x4*)&xvN[i * 4] = *(const f32x4*)(gN + 32 + q * 24 + i * 4);
            *(f32x4*)&efN[0] = *(const f32x4*)(edge_feats + en * 8);
            *(f32x4*)&efN[4] = *(const f32x4*)(edge_feats + en * 8 + 4);
            eaN = *(const f32x4*)(edge_attrs + en * 4);
        }

        // ---- prefetch tile+2s indices
        int snd2 = 0, rcv2 = 0;
        if (has2) {
            int e2 = t2 * 16 + m;
            snd2 = edge_index[e2];
            if (lane < 16) rcv2 = edge_index[N_EDGES + e2];
        }

        // ---- compute current tile (f16 packed A-builds)
        f32x4 z = {0.f, 0.f, 0.f, 0.f};
        f32x4 fA[2] = {z, z}, fB[2] = {z, z}, fD[2] = {z, z};
        f32x4 fC[3][2] = {{z, z}, {z, z}, {z, z}};

#pragma unroll
        for (int ks = 0; ks < 8; ++ks) {
            _Float16 h = (_Float16)efC[ks];
            f16x2 h2 = {h, h};
            {
                f16x8 a = scale8(h2, xs8);
                fA[0] = __builtin_amdgcn_mfma_f32_16x16x32_f16(a, sW8[(0 * 8 + ks) * 64 + lane], fA[0], 0, 0, 0);
                fA[1] = __builtin_amdgcn_mfma_f32_16x16x32_f16(a, sW8[(1 * 8 + ks) * 64 + lane], fA[1], 0, 0, 0);
                fB[0] = __builtin_amdgcn_mfma_f32_16x16x32_f16(a, sW8[(2 * 8 + ks) * 64 + lane], fB[0], 0, 0, 0);
                fB[1] = __builtin_amdgcn_mfma_f32_16x16x32_f16(a, sW8[(3 * 8 + ks) * 64 + lane], fB[1], 0, 0, 0);
            }
            {
                f16x8 bc0 = sW8[(4 * 8 + ks) * 64 + lane];
                f16x8 bc1 = sW8[(5 * 8 + ks) * 64 + lane];
#pragma unroll
                for (int c = 0; c < 3; ++c) {
                    f16x8 a = scale8(h2, xv8[c]);
                    fC[c][0] = __builtin_amdgcn_mfma_f32_16x16x32_f16(a, bc0, fC[c][0], 0, 0, 0);
                    fC[c][1] = __builtin_amdgcn_mfma_f32_16x16x32_f16(a, bc1, fC[c][1], 0, 0, 0);
                }
            }
            {
                f16x8 a = scale8(h2, dt8);
                fD[0] = __builtin_amdgcn_mfma_f32_16x16x32_f16(a, sW8[(6 * 8 + ks) * 64 + lane], fD[0], 0, 0, 0);
                fD[1] = __builtin_amdgcn_mfma_f32_16x16x32_f16(a, sW8[(7 * 8 + ks) * 64 + lane], fD[1], 0, 0, 0);
            }
        }

        // ---- epilogue: per-lane rows q*4+t4; slots+attrs via ds_read_b128
        int4 sl4 = *(const int4*)&sSL[wv][q * 4];
        const int slR[4] = {sl4.x, sl4.y, sl4.z, sl4.w};
#pragma unroll
        for (int t4 = 0; t4 < 4; ++t4) {
            f32x4 ea4 = sEA[wv][q * 4 + t4];
            float ysr = ea4.x, y0r = ea4.y, y1r = ea4.z, y2r = ea4.w;
            int dr = slR[t4];
#pragma unroll
            for (int nt = 0; nt < 2; ++nt) {
                int col = nt * 16 + m;
                float pb = fB[nt][t4];
                int2 pk;
                pk.x = pack2(ysr * fA[nt][t4] + fD[nt][t4],
                             y0r * pb + ysr * fC[0][nt][t4]);
                pk.y = pack2(y1r * pb + ysr * fC[1][nt][t4],
                             y2r * pb + ysr * fC[2][nt][t4]);
                *(int2*)(Msg + (size_t)dr * 128 + col * 4) = pk;
            }
        }

        // ---- rotate pipeline: wait loads land here, convert once
        tile = tn;
        if (hasN) {
            float dtN[8];
            float y0 = eaN.y, y1 = eaN.z, y2 = eaN.w;
#pragma unroll
            for (int j = 0; j < 8; ++j)
                dtN[j] = xvN[j * 3] * y0 + xvN[j * 3 + 1] * y1 + xvN[j * 3 + 2] * y2;
            xs8 = cvt8h(xsN);
#pragma unroll
            for (int c = 0; c < 3; ++c) {
                f16x8 r; f16x2* rp = (f16x2*)&r;
#pragma unroll
                for (int i = 0; i < 4; ++i)
                    rp[i] = pkrtz(xvN[(2 * i) * 3 + c], xvN[(2 * i + 1) * 3 + c]);
                xv8[c] = r;
            }
            dt8 = cvt8h(dtN);
#pragma unroll
            for (int j = 0; j < 8; ++j) efC[j] = efN[j];
            eaC = eaN;
            slC = slN;
            snd1 = snd2;
            rcv1 = rcv2;
        }
    }
}

// ---------------------------------------------------------------------------
// Fused gather + node kernel. Msg/WB now f16. Gather 8-deep batched.
// ---------------------------------------------------------------------------
__global__ __launch_bounds__(256) void node_kernel(
    const float* __restrict__ node_attrs, const unsigned short* __restrict__ Msg,
    const int* __restrict__ cnt, const unsigned short* __restrict__ WB0,
    const unsigned short* __restrict__ WB1, float* __restrict__ out) {
    __shared__ float sM[16][129];
    __shared__ float sAt[16][17];
    int n0 = blockIdx.x * 16;

    int nl = threadIdx.x >> 4;
    int cg = threadIdx.x & 15;
    int n = n0 + nl;
    int s0 = n * SLOTS;
    int s1 = s0 + cnt[n];
    float acc[8];
#pragma unroll
    for (int j = 0; j < 8; ++j) acc[j] = 0.f;
    int s = s0;
    for (; s + 7 < s1; s += 8) {
        f32x4 r[8];
#pragma unroll
        for (int i = 0; i < 8; ++i)
            r[i] = *(const f32x4*)(Msg + (size_t)(s + i) * 128 + cg * 8);
#pragma unroll
        for (int j = 0; j < 8; ++j) {
            float a = 0.f;
#pragma unroll
            for (int i = 0; i < 8; ++i)
                a += f16f(((const unsigned short*)&r[i])[j]);
            acc[j] += a;
        }
    }
    for (; s + 3 < s1; s += 4) {
        f32x4 r0 = *(const f32x4*)(Msg + (size_t)(s + 0) * 128 + cg * 8);
        f32x4 r1 = *(const f32x4*)(Msg + (size_t)(s + 1) * 128 + cg * 8);
        f32x4 r2 = *(const f32x4*)(Msg + (size_t)(s + 2) * 128 + cg * 8);
        f32x4 r3 = *(const f32x4*)(Msg + (size_t)(s + 3) * 128 + cg * 8);
        const unsigned short* u0 = (const unsigned short*)&r0;
        const unsigned short* u1 = (const unsigned short*)&r1;
        const unsigned short* u2 = (const unsigned short*)&r2;
        const unsigned short* u3 = (const unsigned short*)&r3;
#pragma unroll
        for (int j = 0; j < 8; ++j)
            acc[j] += (f16f(u0[j]) + f16f(u1[j])) + (f16f(u2[j]) + f16f(u3[j]));
    }
    for (; s < s1; ++s) {
        f32x4 raw = *(const f32x4*)(Msg + (size_t)s * 128 + cg * 8);
        const unsigned short* us = (const unsigned short*)&raw;
#pragma unroll
        for (int j = 0; j < 8; ++j) acc[j] += f16f(us[j]);
    }
#pragma unroll
    for (int j = 0; j < 8; ++j)
        sM[nl][(j & 3) * 32 + cg * 2 + (j >> 2)] = acc[j];
    sAt[nl][cg] = node_attrs[n * 16 + cg];
    __syncthreads();

    int p = threadIdx.x >> 6;
    int lane = threadIdx.x & 63;
    int m = lane & 15, q = lane >> 4;
    const unsigned short* WB = (p == 0) ? WB0 : WB1;
    int chb = p * 32;
    f32x4 z = {0.f, 0.f, 0.f, 0.f};
    f32x4 D0 = z, D1 = z;
#pragma unroll
    for (int ks = 0; ks < 16; ++ks) {
        int kb = ks * 32 + q * 8;
        float t[8];
#pragma unroll
        for (int j = 0; j < 8; ++j) {
            int k = kb + j;
            t[j] = sM[m][chb + (k >> 4)] * sAt[m][k & 15];
        }
        f16x8 a = cvt8h(t);
        f16x8 b0 = *(const f16x8*)(WB + (ks * 64 + lane) * 8);
        f16x8 b1 = *(const f16x8*)(WB + ((16 + ks) * 64 + lane) * 8);
        D0 = __builtin_amdgcn_mfma_f32_16x16x32_f16(a, b0, D0, 0, 0, 0);
        D1 = __builtin_amdgcn_mfma_f32_16x16x32_f16(a, b1, D1, 0, 0, 0);
    }

#pragma unroll
    for (int t4 = 0; t4 < 4; ++t4) {
        int nl2 = q * 4 + t4;
        int nn = n0 + nl2;
        if (p == 0) {
            out[nn * 128 + m]      = sM[nl2][m] + D0[t4];
            out[nn * 128 + 16 + m] = sM[nl2][16 + m] + D1[t4];
        } else {
            int i = p - 1;
            out[nn * 128 + 32 + m * 3 + i]        = sM[nl2][chb + m] + D0[t4];
            out[nn * 128 + 32 + (16 + m) * 3 + i] = sM[nl2][chb + 16 + m] + D1[t4];
        }
    }
}

extern "C" void kernel_launch(void* const* d_in, const int* in_sizes, int n_in,
                              void* d_out, int out_size, void* d_ws, size_t ws_size,
                              hipStream_t stream) {
    (void)in_sizes; (void)n_in; (void)out_size; (void)ws_size;
    const float* node_attrs = (const float*)d_in[0];
    const float* node_feats = (const float*)d_in[1];
    const float* edge_attrs = (const float*)d_in[2];
    const float* edge_feats = (const float*)d_in[3];
    const int*   edge_index = (const int*)d_in[4];
    const float* Wgen = (const float*)d_in[5];
    const float* L1s  = (const float*)d_in[6];
    const float* L1v  = (const float*)d_in[7];
    const float* WS0  = (const float*)d_in[8];
    const float* WS1  = (const float*)d_in[9];
    const float* L2s  = (const float*)d_in[10];
    const float* L2v  = (const float*)d_in[11];
    float* out = (float*)d_out;
    char* ws = (char*)d_ws;

    // Msg: N_NODES*SLOTS rows x 128 f16 = 102,400,000 B (ws is 256 MiB)
    unsigned short* Msg = (unsigned short*)ws;
    unsigned short* Wc  = (unsigned short*)(ws + 102400000);   // 65,536
    unsigned short* WB0 = (unsigned short*)(ws + 102465536);   // 32,768
    unsigned short* WB1 = (unsigned short*)(ws + 102498304);   // 32,768
    int* cnt = (int*)(ws + 102531072);                         // 10000 ints

    prep_kernel<<<64, 1024, 0, stream>>>(Wgen, L1s, L1v, WS0, WS1, L2s, L2v,
                                         Wc, WB0, WB1, cnt);
    edge_kernel<<<512, 256, 0, stream>>>(node_feats, edge_attrs, edge_feats,
                                         edge_index, Wc, cnt, Msg);
    node_kernel<<<625, 256, 0, stream>>>(node_attrs, Msg, cnt, WB0, WB1, out);
}